// Round 8
// baseline (821.377 us; speedup 1.0000x reference)
//
#include <hip/hip_runtime.h>
#include <hip/hip_bf16.h>

#define NN 50000
#define NE 1600000
#define DIM 128
#define NG 64
#define EPSV 1e-5f
#define NCHUNK 49   // ceil(50000/1024)
#define RUN 4       // nodes per wave in pool kernel (segment aggregation)
#define NXCD 8
#define SHARD_COLS (NN / NXCD)   // 6250
#define FILL_CHUNKS 256          // edge chunks; grid = 8 * FILL_CHUNKS
// feature slicing: 8 slices x 16 cols; slice tables are 50000*32B = 1.6MB,
// L2-resident per XCD via blockIdx&7 -> XCD round-robin affinity.
#define SLICES 8

typedef __attribute__((ext_vector_type(8))) __bf16 bf16x8;
typedef __attribute__((ext_vector_type(2))) __bf16 bf16x2;
typedef __attribute__((ext_vector_type(16))) float f32x16;

// ---------------- CSR build ----------------

__global__ void count_kernel(const int* __restrict__ ecol, int* __restrict__ cnt) {
    int e = blockIdx.x * 256 + threadIdx.x;
    if (e < NE) atomicAdd(&cnt[__builtin_nontemporal_load(&ecol[e])], 1);
}

__global__ void scan_chunk(const int* __restrict__ cnt, int* __restrict__ excl,
                           int* __restrict__ csum) {
    __shared__ int lds[256];
    int t = threadIdx.x;
    int base = blockIdx.x * 1024 + t * 4;
    int v0 = (base + 0 < NN) ? cnt[base + 0] : 0;
    int v1 = (base + 1 < NN) ? cnt[base + 1] : 0;
    int v2 = (base + 2 < NN) ? cnt[base + 2] : 0;
    int v3 = (base + 3 < NN) ? cnt[base + 3] : 0;
    int s = v0 + v1 + v2 + v3;
    lds[t] = s;
    __syncthreads();
    for (int off = 1; off < 256; off <<= 1) {
        int x = (t >= off) ? lds[t - off] : 0;
        __syncthreads();
        lds[t] += x;
        __syncthreads();
    }
    int run = lds[t] - s;           // exclusive prefix within chunk
    if (t == 255) csum[blockIdx.x] = lds[t];
    if (base + 0 < NN) excl[base + 0] = run; run += v0;
    if (base + 1 < NN) excl[base + 1] = run; run += v1;
    if (base + 2 < NN) excl[base + 2] = run; run += v2;
    if (base + 3 < NN) excl[base + 3] = run;
}

__global__ void scan_tail(const int* __restrict__ csum, int* __restrict__ coff, int nch) {
    int l = threadIdx.x;
    int v = (l < nch) ? csum[l] : 0;
    int s = v;
    for (int o = 1; o < 64; o <<= 1) {
        int x = __shfl_up(s, o);
        if (l >= o) s += x;
    }
    if (l < nch) coff[l] = s - v;   // exclusive chunk offsets
}

__global__ void fixup_kernel(int* __restrict__ row_ptr, const int* __restrict__ coff,
                             const int* __restrict__ cnt, float* __restrict__ dinv,
                             int* __restrict__ cursor) {
    int n = blockIdx.x * 256 + threadIdx.x;
    if (n < NN) {
        int rp = row_ptr[n] + coff[n >> 10];
        row_ptr[n] = rp;
        cursor[n] = rp;
        dinv[n] = rsqrtf((float)(cnt[n] + 1));   // +1 for self-loop
    }
    if (n == 0) row_ptr[NN] = NE;
}

// XCD-sharded scatter: block b handles col-shard (b&7) over edge-chunk (b>>3).
__global__ void fill_kernel(const int* __restrict__ erow, const int* __restrict__ ecol,
                            int* __restrict__ cursor, int* __restrict__ esrc) {
    const int shard = blockIdx.x & (NXCD - 1);
    const int chunk = blockIdx.x >> 3;
    const int lo = shard * SHARD_COLS;
    const int hi = lo + SHARD_COLS;       // NN divisible by 8
    for (int e = chunk * 256 + threadIdx.x; e < NE; e += FILL_CHUNKS * 256) {
        const int c = __builtin_nontemporal_load(&ecol[e]);
        if (c >= lo && c < hi) {
            int pos = atomicAdd(&cursor[c], 1);
            esrc[pos] = __builtin_nontemporal_load(&erow[e]);
        }
    }
}

// fold bias+BN into per-col scale/shift:  out = acc*scale + shift
__global__ void bn_prep_kernel(const float* __restrict__ b1, const float* __restrict__ g1,
                               const float* __restrict__ be1, const float* __restrict__ rm1,
                               const float* __restrict__ rv1,
                               const float* __restrict__ b2, const float* __restrict__ g2,
                               const float* __restrict__ be2, const float* __restrict__ rm2,
                               const float* __restrict__ rv2,
                               float* __restrict__ sc1, float* __restrict__ sh1,
                               float* __restrict__ sc2, float* __restrict__ sh2) {
    int c = threadIdx.x;
    if (c < DIM) {
        float s1 = g1[c] * rsqrtf(rv1[c] + EPSV);
        sc1[c] = s1;
        sh1[c] = (b1[c] - rm1[c]) * s1 + be1[c];
        float s2 = g2[c] * rsqrtf(rv2[c] + EPSV);
        sc2[c] = s2;
        sh2[c] = (b2[c] - rm2[c]) * s2 + be2[c];
    }
}

// ---------------- dense: (h @ W) * dinv[row] -> sliced bf16 table ----------
// Table layout: elem(slice, n, c) = slice*NN*16 + n*16 + c   (c in [0,16))

__device__ __forceinline__ bf16x8 load8(const float* p) {
    float4 lo = ((const float4*)p)[0], hi = ((const float4*)p)[1];
    bf16x8 a;
    a[0] = (__bf16)lo.x; a[1] = (__bf16)lo.y; a[2] = (__bf16)lo.z; a[3] = (__bf16)lo.w;
    a[4] = (__bf16)hi.x; a[5] = (__bf16)hi.y; a[6] = (__bf16)hi.z; a[7] = (__bf16)hi.w;
    return a;
}
__device__ __forceinline__ bf16x8 load8(const __bf16* p) {
    return *(const bf16x8*)p;
}

template <typename T, bool SLICED_IN>
__global__ void __launch_bounds__(256) matmul_kernel(const T* __restrict__ h,
                                                     const float* __restrict__ W,
                                                     const float* __restrict__ dinv,
                                                     __bf16* __restrict__ t) {
    const int wave = threadIdx.x >> 6;
    const int lane = threadIdx.x & 63;
    const int col = wave * 32 + (lane & 31);
    const int khalf = (lane >> 5) * 8;   // 0 or 8

    bf16x8 b[8];
#pragma unroll
    for (int kc = 0; kc < 8; kc++) {
#pragma unroll
        for (int j = 0; j < 8; j++) {
            b[kc][j] = (__bf16)W[(kc * 16 + khalf + j) * DIM + col];
        }
    }

    const int ntiles = (NN + 31) / 32;
    for (int tile = blockIdx.x; tile < ntiles; tile += gridDim.x) {
        const int arow = tile * 32 + (lane & 31);
        const int arow_c = (arow < NN) ? arow : (NN - 1);  // clamped load; bad rows not stored
        f32x16 acc = {};
#pragma unroll
        for (int kc = 0; kc < 8; kc++) {
            const T* p = SLICED_IN
                ? h + (size_t)kc * NN * 16 + (size_t)arow_c * 16 + khalf
                : h + (size_t)arow_c * DIM + kc * 16 + khalf;
            bf16x8 a = load8(p);
            acc = __builtin_amdgcn_mfma_f32_32x32x16_bf16(a, b[kc], acc, 0, 0, 0);
        }
        const size_t sbase = (size_t)(col >> 4) * NN * 16 + (col & 15);
#pragma unroll
        for (int r = 0; r < 16; r++) {
            int orow = tile * 32 + (r & 3) + 8 * (r >> 2) + 4 * (lane >> 5);
            if (orow < NN) t[sbase + (size_t)orow * 16] = (__bf16)(acc[r] * dinv[orow]);
        }
    }
}

// ---------------- sparse: sliced pull-gather ----------------
// slice = blockIdx&7 -> pinned to one XCD (round-robin dispatch), whose L2
// holds the whole 1.6MB slice table. Wave = one dst node; 8 lane-groups of 8
// lanes read 8 edges' 32B row-slices per instruction; epilogue reduces over
// groups with 3 shfl_xor. Rows pre-scaled by dinv[src]; sum is unweighted.

__device__ __forceinline__ float lo16(unsigned u) { return __uint_as_float(u << 16); }
__device__ __forceinline__ float hi16(unsigned u) { return __uint_as_float(u & 0xffff0000u); }

__device__ __forceinline__ void gather_slice(
    const unsigned* __restrict__ ts, const int* __restrict__ esrc,
    int beg, int end, int grp, int sub, float& ax, float& ay) {
    if (beg >= end) return;
    int sA; float wA; unsigned uA;
    {
        const int ee = beg + grp;
        const bool ok = ee < end;
        sA = __builtin_nontemporal_load(&esrc[ok ? ee : beg]);
        wA = ok ? 1.f : 0.f;
        uA = ts[(size_t)sA * 8 + sub];
    }
    for (int e = beg; e < end;) {
        const int e2 = e + 8;
        int sB; float wB; unsigned uB;
        if (e2 < end) {
            const int ee = e2 + grp;
            const bool ok = ee < end;
            sB = __builtin_nontemporal_load(&esrc[ok ? ee : beg]);
            wB = ok ? 1.f : 0.f;
            uB = ts[(size_t)sB * 8 + sub];
        }
        ax = fmaf(lo16(uA), wA, ax);
        ay = fmaf(hi16(uA), wA, ay);
        e = e2;
        sA = sB; wA = wB; uA = uB;
    }
}

__global__ void __launch_bounds__(256) gather_bn_kernel(
    const unsigned* __restrict__ t32, const int* __restrict__ row_ptr,
    const int* __restrict__ esrc, const float* __restrict__ dinv,
    const float* __restrict__ scale, const float* __restrict__ shift,
    __bf16* __restrict__ out) {
    const int slice = blockIdx.x & (SLICES - 1);
    const int lane = threadIdx.x & 63;
    const int grp = lane >> 3, sub = lane & 7;
    const int n = __builtin_amdgcn_readfirstlane((blockIdx.x >> 3) * 4 + (threadIdx.x >> 6));
    if (n >= NN) return;
    const unsigned* ts = t32 + (size_t)slice * NN * 8;
    const int beg = row_ptr[n], end = row_ptr[n + 1];
    float ax = 0.f, ay = 0.f;
    gather_slice(ts, esrc, beg, end, grp, sub, ax, ay);
    ax += __shfl_xor(ax, 8); ax += __shfl_xor(ax, 16); ax += __shfl_xor(ax, 32);
    ay += __shfl_xor(ay, 8); ay += __shfl_xor(ay, 16); ay += __shfl_xor(ay, 32);
    if (lane < 8) {
        const unsigned u = ts[(size_t)n * 8 + lane];   // self loop
        ax += lo16(u); ay += hi16(u);
        const float dv = dinv[n];
        const int c0 = slice * 16 + lane * 2;
        const float vx = fmaxf(fmaf(ax, dv * scale[c0], shift[c0]), 0.f);
        const float vy = fmaxf(fmaf(ay, dv * scale[c0 + 1], shift[c0 + 1]), 0.f);
        bf16x2 o; o[0] = (__bf16)vx; o[1] = (__bf16)vy;
        *(bf16x2*)(out + (size_t)slice * NN * 16 + (size_t)n * 16 + lane * 2) = o;
    }
}

// Pool: batch is SORTED -> segment reduction per wave over RUN nodes; flush
// atomics (lanes 0-7, 16 cols of this slice) only at graph boundary / run end.

__global__ void __launch_bounds__(256) gather_pool_kernel(
    const unsigned* __restrict__ t32, const int* __restrict__ row_ptr,
    const int* __restrict__ esrc, const float* __restrict__ dinv,
    const float* __restrict__ bias, const int* __restrict__ batch,
    float* __restrict__ out) {
    const int slice = blockIdx.x & (SLICES - 1);
    const int lane = threadIdx.x & 63;
    const int grp = lane >> 3, sub = lane & 7;
    const int wid = __builtin_amdgcn_readfirstlane((blockIdx.x >> 3) * 4 + (threadIdx.x >> 6));
    const int n0 = wid * RUN;            // NN % RUN == 0
    if (n0 >= NN) return;
    const unsigned* ts = t32 + (size_t)slice * NN * 8;
    const int c0 = slice * 16 + sub * 2;
    const float bx = bias[c0], by = bias[c0 + 1];
    float rx = 0.f, ry = 0.f;
    int g = batch[n0];
    for (int j = 0; j < RUN; j++) {
        const int n = n0 + j;
        const int beg = row_ptr[n], end = row_ptr[n + 1];
        float ax = 0.f, ay = 0.f;
        gather_slice(ts, esrc, beg, end, grp, sub, ax, ay);
        ax += __shfl_xor(ax, 8); ax += __shfl_xor(ax, 16); ax += __shfl_xor(ax, 32);
        ay += __shfl_xor(ay, 8); ay += __shfl_xor(ay, 16); ay += __shfl_xor(ay, 32);
        const unsigned u = ts[(size_t)n * 8 + sub];   // self loop (dup across groups)
        ax += lo16(u); ay += hi16(u);
        const float dv = dinv[n];
        const int gn = batch[n];
        if (gn != g) {   // graph boundary (wave-uniform branch)
            if (lane < 8) {
                atomicAdd(out + (size_t)g * DIM + c0, rx);
                atomicAdd(out + (size_t)g * DIM + c0 + 1, ry);
            }
            rx = 0.f; ry = 0.f; g = gn;
        }
        rx += fmaf(ax, dv, bx);
        ry += fmaf(ay, dv, by);
    }
    if (lane < 8) {
        atomicAdd(out + (size_t)g * DIM + c0, rx);
        atomicAdd(out + (size_t)g * DIM + c0 + 1, ry);
    }
}

// ---------------- launch ----------------

extern "C" void kernel_launch(void* const* d_in, const int* in_sizes, int n_in,
                              void* d_out, int out_size, void* d_ws, size_t ws_size,
                              hipStream_t stream) {
    const float* x    = (const float*)d_in[0];
    const int*   ei   = (const int*)d_in[1];
    const int*   batch= (const int*)d_in[2];
    const float* W1 = (const float*)d_in[3];
    const float* b1 = (const float*)d_in[4];
    const float* W2 = (const float*)d_in[5];
    const float* b2 = (const float*)d_in[6];
    const float* W3 = (const float*)d_in[7];
    const float* b3 = (const float*)d_in[8];
    const float* g1 = (const float*)d_in[9];
    const float* be1= (const float*)d_in[10];
    const float* rm1= (const float*)d_in[11];
    const float* rv1= (const float*)d_in[12];
    const float* g2 = (const float*)d_in[13];
    const float* be2= (const float*)d_in[14];
    const float* rm2= (const float*)d_in[15];
    const float* rv2= (const float*)d_in[16];
    const int* erow = ei;
    const int* ecol = ei + NE;

    char* ws = (char*)d_ws;
    size_t off = 0;
    auto alloc = [&](size_t bytes) -> void* {
        void* p = ws + off;
        off = (off + bytes + 255) & ~(size_t)255;
        return p;
    };
    int*    cnt     = (int*)alloc(NN * sizeof(int));
    int*    row_ptr = (int*)alloc((NN + 1) * sizeof(int));
    int*    cursor  = (int*)alloc(NN * sizeof(int));
    int*    csum    = (int*)alloc(64 * sizeof(int));
    int*    coff    = (int*)alloc(64 * sizeof(int));
    float*  dinv    = (float*)alloc(NN * sizeof(float));
    int*    esrc    = (int*)alloc(NE * sizeof(int));
    __bf16* tbuf    = (__bf16*)alloc((size_t)NN * DIM * sizeof(__bf16));
    __bf16* hbuf    = (__bf16*)alloc((size_t)NN * DIM * sizeof(__bf16));
    float*  sc1     = (float*)alloc(DIM * sizeof(float));
    float*  sh1     = (float*)alloc(DIM * sizeof(float));
    float*  sc2     = (float*)alloc(DIM * sizeof(float));
    float*  sh2     = (float*)alloc(DIM * sizeof(float));

    hipMemsetAsync(cnt, 0, NN * sizeof(int), stream);
    hipMemsetAsync(d_out, 0, NG * DIM * sizeof(float), stream);

    bn_prep_kernel<<<1, 128, 0, stream>>>(b1, g1, be1, rm1, rv1,
                                          b2, g2, be2, rm2, rv2,
                                          sc1, sh1, sc2, sh2);
    count_kernel<<<(NE + 255) / 256, 256, 0, stream>>>(ecol, cnt);
    scan_chunk<<<NCHUNK, 256, 0, stream>>>(cnt, row_ptr, csum);
    scan_tail<<<1, 64, 0, stream>>>(csum, coff, NCHUNK);
    fixup_kernel<<<(NN + 255) / 256, 256, 0, stream>>>(row_ptr, coff, cnt, dinv, cursor);
    fill_kernel<<<NXCD * FILL_CHUNKS, 256, 0, stream>>>(erow, ecol, cursor, esrc);

    const unsigned* t32 = (const unsigned*)tbuf;
    const int nblk_bn = SLICES * ((NN + 3) / 4);
    const int nblk_pool = SLICES * ((NN / RUN + 3) / 4);

    matmul_kernel<float, false><<<512, 256, 0, stream>>>(x, W1, dinv, tbuf);
    gather_bn_kernel<<<nblk_bn, 256, 0, stream>>>(t32, row_ptr, esrc, dinv,
                                                  sc1, sh1, hbuf);
    matmul_kernel<__bf16, true><<<512, 256, 0, stream>>>(hbuf, W2, dinv, tbuf);
    gather_bn_kernel<<<nblk_bn, 256, 0, stream>>>(t32, row_ptr, esrc, dinv,
                                                  sc2, sh2, hbuf);
    matmul_kernel<__bf16, true><<<512, 256, 0, stream>>>(hbuf, W3, dinv, tbuf);
    gather_pool_kernel<<<nblk_pool, 256, 0, stream>>>(t32, row_ptr, esrc, dinv,
                                                      b3, batch, (float*)d_out);
}

// Round 9
// 503.122 us; speedup vs baseline: 1.6326x; 1.6326x over previous
//
#include <hip/hip_runtime.h>
#include <hip/hip_bf16.h>

#define NN 50000
#define NE 1600000
#define DIM 128
#define NG 64
#define EPSV 1e-5f
#define NCHUNK 49   // ceil(50000/1024)
#define RUN 4       // nodes per wave in pool kernel (segment aggregation)
#define NXCD 8
#define SHARD_COLS (NN / NXCD)   // 6250
#define FILL_CHUNKS 256          // edge chunks; grid = 8 * FILL_CHUNKS
// feature slicing: 4 slices x 32 cols; slice table = 50000*64B = 3.2MB,
// L2-resident per XCD-pair via blockIdx&3 (round-robin blockIdx->XCD).
#define SLICES 4
#define UNROLL 8     // independent table loads in flight per wave

typedef __attribute__((ext_vector_type(8))) __bf16 bf16x8;
typedef __attribute__((ext_vector_type(2))) __bf16 bf16x2;
typedef __attribute__((ext_vector_type(16))) float f32x16;

// ---------------- CSR build ----------------

__global__ void count_kernel(const int* __restrict__ ecol, int* __restrict__ cnt) {
    int e = blockIdx.x * 256 + threadIdx.x;
    if (e < NE) atomicAdd(&cnt[__builtin_nontemporal_load(&ecol[e])], 1);
}

__global__ void scan_chunk(const int* __restrict__ cnt, int* __restrict__ excl,
                           int* __restrict__ csum) {
    __shared__ int lds[256];
    int t = threadIdx.x;
    int base = blockIdx.x * 1024 + t * 4;
    int v0 = (base + 0 < NN) ? cnt[base + 0] : 0;
    int v1 = (base + 1 < NN) ? cnt[base + 1] : 0;
    int v2 = (base + 2 < NN) ? cnt[base + 2] : 0;
    int v3 = (base + 3 < NN) ? cnt[base + 3] : 0;
    int s = v0 + v1 + v2 + v3;
    lds[t] = s;
    __syncthreads();
    for (int off = 1; off < 256; off <<= 1) {
        int x = (t >= off) ? lds[t - off] : 0;
        __syncthreads();
        lds[t] += x;
        __syncthreads();
    }
    int run = lds[t] - s;           // exclusive prefix within chunk
    if (t == 255) csum[blockIdx.x] = lds[t];
    if (base + 0 < NN) excl[base + 0] = run; run += v0;
    if (base + 1 < NN) excl[base + 1] = run; run += v1;
    if (base + 2 < NN) excl[base + 2] = run; run += v2;
    if (base + 3 < NN) excl[base + 3] = run;
}

__global__ void scan_tail(const int* __restrict__ csum, int* __restrict__ coff, int nch) {
    int l = threadIdx.x;
    int v = (l < nch) ? csum[l] : 0;
    int s = v;
    for (int o = 1; o < 64; o <<= 1) {
        int x = __shfl_up(s, o);
        if (l >= o) s += x;
    }
    if (l < nch) coff[l] = s - v;   // exclusive chunk offsets
}

__global__ void fixup_kernel(int* __restrict__ row_ptr, const int* __restrict__ coff,
                             const int* __restrict__ cnt, float* __restrict__ dinv,
                             int* __restrict__ cursor) {
    int n = blockIdx.x * 256 + threadIdx.x;
    if (n < NN) {
        int rp = row_ptr[n] + coff[n >> 10];
        row_ptr[n] = rp;
        cursor[n] = rp;
        dinv[n] = rsqrtf((float)(cnt[n] + 1));   // +1 for self-loop
    }
    if (n == 0) row_ptr[NN] = NE;
}

// XCD-sharded scatter: block b handles col-shard (b&7) over edge-chunk (b>>3).
__global__ void fill_kernel(const int* __restrict__ erow, const int* __restrict__ ecol,
                            int* __restrict__ cursor, int* __restrict__ esrc) {
    const int shard = blockIdx.x & (NXCD - 1);
    const int chunk = blockIdx.x >> 3;
    const int lo = shard * SHARD_COLS;
    const int hi = lo + SHARD_COLS;       // NN divisible by 8
    for (int e = chunk * 256 + threadIdx.x; e < NE; e += FILL_CHUNKS * 256) {
        const int c = __builtin_nontemporal_load(&ecol[e]);
        if (c >= lo && c < hi) {
            int pos = atomicAdd(&cursor[c], 1);
            esrc[pos] = __builtin_nontemporal_load(&erow[e]);
        }
    }
}

// fold bias+BN into per-col scale/shift:  out = acc*scale + shift
__global__ void bn_prep_kernel(const float* __restrict__ b1, const float* __restrict__ g1,
                               const float* __restrict__ be1, const float* __restrict__ rm1,
                               const float* __restrict__ rv1,
                               const float* __restrict__ b2, const float* __restrict__ g2,
                               const float* __restrict__ be2, const float* __restrict__ rm2,
                               const float* __restrict__ rv2,
                               float* __restrict__ sc1, float* __restrict__ sh1,
                               float* __restrict__ sc2, float* __restrict__ sh2) {
    int c = threadIdx.x;
    if (c < DIM) {
        float s1 = g1[c] * rsqrtf(rv1[c] + EPSV);
        sc1[c] = s1;
        sh1[c] = (b1[c] - rm1[c]) * s1 + be1[c];
        float s2 = g2[c] * rsqrtf(rv2[c] + EPSV);
        sc2[c] = s2;
        sh2[c] = (b2[c] - rm2[c]) * s2 + be2[c];
    }
}

// ---------------- dense: (h @ W) * dinv[row] -> sliced bf16 table ----------
// Table layout (bf16 units): elem(slice, n, c) = slice*NN*32 + n*32 + c, c in [0,32)

__device__ __forceinline__ bf16x8 load8(const float* p) {
    float4 lo = ((const float4*)p)[0], hi = ((const float4*)p)[1];
    bf16x8 a;
    a[0] = (__bf16)lo.x; a[1] = (__bf16)lo.y; a[2] = (__bf16)lo.z; a[3] = (__bf16)lo.w;
    a[4] = (__bf16)hi.x; a[5] = (__bf16)hi.y; a[6] = (__bf16)hi.z; a[7] = (__bf16)hi.w;
    return a;
}
__device__ __forceinline__ bf16x8 load8(const __bf16* p) {
    return *(const bf16x8*)p;
}

template <typename T, bool SLICED_IN>
__global__ void __launch_bounds__(256) matmul_kernel(const T* __restrict__ h,
                                                     const float* __restrict__ W,
                                                     const float* __restrict__ dinv,
                                                     __bf16* __restrict__ t) {
    const int wave = threadIdx.x >> 6;
    const int lane = threadIdx.x & 63;
    const int col = wave * 32 + (lane & 31);
    const int khalf = (lane >> 5) * 8;   // 0 or 8

    bf16x8 b[8];
#pragma unroll
    for (int kc = 0; kc < 8; kc++) {
#pragma unroll
        for (int j = 0; j < 8; j++) {
            b[kc][j] = (__bf16)W[(kc * 16 + khalf + j) * DIM + col];
        }
    }

    const int ntiles = (NN + 31) / 32;
    for (int tile = blockIdx.x; tile < ntiles; tile += gridDim.x) {
        const int arow = tile * 32 + (lane & 31);
        const int arow_c = (arow < NN) ? arow : (NN - 1);  // clamped load; bad rows not stored
        f32x16 acc = {};
#pragma unroll
        for (int kc = 0; kc < 8; kc++) {
            const int col0 = kc * 16 + khalf;      // multiple of 8; stays inside one slice
            const T* p = SLICED_IN
                ? h + (size_t)(col0 >> 5) * NN * 32 + (size_t)arow_c * 32 + (col0 & 31)
                : h + (size_t)arow_c * DIM + col0;
            bf16x8 a = load8(p);
            acc = __builtin_amdgcn_mfma_f32_32x32x16_bf16(a, b[kc], acc, 0, 0, 0);
        }
        const size_t sbase = (size_t)(col >> 5) * NN * 32 + (col & 31);
#pragma unroll
        for (int r = 0; r < 16; r++) {
            int orow = tile * 32 + (r & 3) + 8 * (r >> 2) + 4 * (lane >> 5);
            if (orow < NN) t[sbase + (size_t)orow * 32] = (__bf16)(acc[r] * dinv[orow]);
        }
    }
}

// ---------------- sparse: sliced pull-gather, r6 access shape ----------------
// slice = blockIdx&3 -> pinned to XCD pair {s,s+4}; 3.2MB slice is L2-resident.
// Wave = one dst node. 4 lane-groups of 16 lanes; one instruction loads 4
// edges' 64B row-slices (u32 per lane). UNROLL=8 instructions in flight
// = 32 edges per iteration, 8 independent loads (r2-proven MLP).
// Rows pre-scaled by dinv[src]; sum is unweighted; pad slots clamp to
// esrc[beg] with weight 0 (cache-hot).

__device__ __forceinline__ float lo16(unsigned u) { return __uint_as_float(u << 16); }
__device__ __forceinline__ float hi16(unsigned u) { return __uint_as_float(u & 0xffff0000u); }

__device__ __forceinline__ void gather_slice(
    const unsigned* __restrict__ ts, const int* __restrict__ esrc,
    int beg, int end, int grp, int sub, float& ax, float& ay) {
    for (int e = beg; e < end; e += UNROLL * 4) {
        int s[UNROLL];
        float w[UNROLL];
        unsigned u[UNROLL];
#pragma unroll
        for (int i = 0; i < UNROLL; i++) {
            const int ee = e + i * 4 + grp;
            const bool ok = ee < end;
            s[i] = __builtin_nontemporal_load(&esrc[ok ? ee : beg]);
            w[i] = ok ? 1.f : 0.f;
        }
#pragma unroll
        for (int i = 0; i < UNROLL; i++) u[i] = ts[(size_t)s[i] * 16 + sub];
#pragma unroll
        for (int i = 0; i < UNROLL; i++) {
            ax = fmaf(lo16(u[i]), w[i], ax);
            ay = fmaf(hi16(u[i]), w[i], ay);
        }
    }
}

__global__ void __launch_bounds__(256) gather_bn_kernel(
    const unsigned* __restrict__ t32, const int* __restrict__ row_ptr,
    const int* __restrict__ esrc, const float* __restrict__ dinv,
    const float* __restrict__ scale, const float* __restrict__ shift,
    __bf16* __restrict__ out) {
    const int slice = blockIdx.x & (SLICES - 1);
    const int lane = threadIdx.x & 63;
    const int grp = lane >> 4, sub = lane & 15;
    const int n = __builtin_amdgcn_readfirstlane((blockIdx.x >> 2) * 4 + (threadIdx.x >> 6));
    if (n >= NN) return;
    const unsigned* ts = t32 + (size_t)slice * NN * 16;
    const int beg = row_ptr[n], end = row_ptr[n + 1];
    float ax = 0.f, ay = 0.f;
    gather_slice(ts, esrc, beg, end, grp, sub, ax, ay);
    ax += __shfl_xor(ax, 16); ax += __shfl_xor(ax, 32);
    ay += __shfl_xor(ay, 16); ay += __shfl_xor(ay, 32);
    if (lane < 16) {
        const unsigned u = ts[(size_t)n * 16 + lane];   // self loop
        ax += lo16(u); ay += hi16(u);
        const float dv = dinv[n];
        const int c0 = slice * 32 + lane * 2;
        const float vx = fmaxf(fmaf(ax, dv * scale[c0], shift[c0]), 0.f);
        const float vy = fmaxf(fmaf(ay, dv * scale[c0 + 1], shift[c0 + 1]), 0.f);
        bf16x2 o; o[0] = (__bf16)vx; o[1] = (__bf16)vy;
        *(bf16x2*)(out + (size_t)slice * NN * 32 + (size_t)n * 32 + lane * 2) = o;
    }
}

// Pool: batch is SORTED -> segment reduction per wave over RUN nodes; flush
// atomics (lanes 0-15, 32 cols of this slice) only at graph boundary / run end.

__global__ void __launch_bounds__(256) gather_pool_kernel(
    const unsigned* __restrict__ t32, const int* __restrict__ row_ptr,
    const int* __restrict__ esrc, const float* __restrict__ dinv,
    const float* __restrict__ bias, const int* __restrict__ batch,
    float* __restrict__ out) {
    const int slice = blockIdx.x & (SLICES - 1);
    const int lane = threadIdx.x & 63;
    const int grp = lane >> 4, sub = lane & 15;
    const int wid = __builtin_amdgcn_readfirstlane((blockIdx.x >> 2) * 4 + (threadIdx.x >> 6));
    const int n0 = wid * RUN;            // NN % RUN == 0
    if (n0 >= NN) return;
    const unsigned* ts = t32 + (size_t)slice * NN * 16;
    const int c0 = slice * 32 + sub * 2;
    const float bx = bias[c0], by = bias[c0 + 1];
    float rx = 0.f, ry = 0.f;
    int g = batch[n0];
    for (int j = 0; j < RUN; j++) {
        const int n = n0 + j;
        const int beg = row_ptr[n], end = row_ptr[n + 1];
        float ax = 0.f, ay = 0.f;
        gather_slice(ts, esrc, beg, end, grp, sub, ax, ay);
        ax += __shfl_xor(ax, 16); ax += __shfl_xor(ax, 32);
        ay += __shfl_xor(ay, 16); ay += __shfl_xor(ay, 32);
        const unsigned u = ts[(size_t)n * 16 + sub];   // self loop (dup across groups ok)
        ax += lo16(u); ay += hi16(u);
        const float dv = dinv[n];
        const int gn = batch[n];
        if (gn != g) {   // graph boundary (wave-uniform branch)
            if (lane < 16) {
                atomicAdd(out + (size_t)g * DIM + c0, rx);
                atomicAdd(out + (size_t)g * DIM + c0 + 1, ry);
            }
            rx = 0.f; ry = 0.f; g = gn;
        }
        rx += fmaf(ax, dv, bx);
        ry += fmaf(ay, dv, by);
    }
    if (lane < 16) {
        atomicAdd(out + (size_t)g * DIM + c0, rx);
        atomicAdd(out + (size_t)g * DIM + c0 + 1, ry);
    }
}

// ---------------- launch ----------------

extern "C" void kernel_launch(void* const* d_in, const int* in_sizes, int n_in,
                              void* d_out, int out_size, void* d_ws, size_t ws_size,
                              hipStream_t stream) {
    const float* x    = (const float*)d_in[0];
    const int*   ei   = (const int*)d_in[1];
    const int*   batch= (const int*)d_in[2];
    const float* W1 = (const float*)d_in[3];
    const float* b1 = (const float*)d_in[4];
    const float* W2 = (const float*)d_in[5];
    const float* b2 = (const float*)d_in[6];
    const float* W3 = (const float*)d_in[7];
    const float* b3 = (const float*)d_in[8];
    const float* g1 = (const float*)d_in[9];
    const float* be1= (const float*)d_in[10];
    const float* rm1= (const float*)d_in[11];
    const float* rv1= (const float*)d_in[12];
    const float* g2 = (const float*)d_in[13];
    const float* be2= (const float*)d_in[14];
    const float* rm2= (const float*)d_in[15];
    const float* rv2= (const float*)d_in[16];
    const int* erow = ei;
    const int* ecol = ei + NE;

    char* ws = (char*)d_ws;
    size_t off = 0;
    auto alloc = [&](size_t bytes) -> void* {
        void* p = ws + off;
        off = (off + bytes + 255) & ~(size_t)255;
        return p;
    };
    int*    cnt     = (int*)alloc(NN * sizeof(int));
    int*    row_ptr = (int*)alloc((NN + 1) * sizeof(int));
    int*    cursor  = (int*)alloc(NN * sizeof(int));
    int*    csum    = (int*)alloc(64 * sizeof(int));
    int*    coff    = (int*)alloc(64 * sizeof(int));
    float*  dinv    = (float*)alloc(NN * sizeof(float));
    int*    esrc    = (int*)alloc(NE * sizeof(int));
    __bf16* tbuf    = (__bf16*)alloc((size_t)NN * DIM * sizeof(__bf16));
    __bf16* hbuf    = (__bf16*)alloc((size_t)NN * DIM * sizeof(__bf16));
    float*  sc1     = (float*)alloc(DIM * sizeof(float));
    float*  sh1     = (float*)alloc(DIM * sizeof(float));
    float*  sc2     = (float*)alloc(DIM * sizeof(float));
    float*  sh2     = (float*)alloc(DIM * sizeof(float));

    hipMemsetAsync(cnt, 0, NN * sizeof(int), stream);
    hipMemsetAsync(d_out, 0, NG * DIM * sizeof(float), stream);

    bn_prep_kernel<<<1, 128, 0, stream>>>(b1, g1, be1, rm1, rv1,
                                          b2, g2, be2, rm2, rv2,
                                          sc1, sh1, sc2, sh2);
    count_kernel<<<(NE + 255) / 256, 256, 0, stream>>>(ecol, cnt);
    scan_chunk<<<NCHUNK, 256, 0, stream>>>(cnt, row_ptr, csum);
    scan_tail<<<1, 64, 0, stream>>>(csum, coff, NCHUNK);
    fixup_kernel<<<(NN + 255) / 256, 256, 0, stream>>>(row_ptr, coff, cnt, dinv, cursor);
    fill_kernel<<<NXCD * FILL_CHUNKS, 256, 0, stream>>>(erow, ecol, cursor, esrc);

    const unsigned* t32 = (const unsigned*)tbuf;
    const int nblk_bn = SLICES * ((NN + 3) / 4);          // slice in low 2 bits
    const int nblk_pool = SLICES * ((NN / RUN + 3) / 4);

    matmul_kernel<float, false><<<512, 256, 0, stream>>>(x, W1, dinv, tbuf);
    gather_bn_kernel<<<nblk_bn, 256, 0, stream>>>(t32, row_ptr, esrc, dinv,
                                                  sc1, sh1, hbuf);
    matmul_kernel<__bf16, true><<<512, 256, 0, stream>>>(hbuf, W2, dinv, tbuf);
    gather_bn_kernel<<<nblk_bn, 256, 0, stream>>>(t32, row_ptr, esrc, dinv,
                                                  sc2, sh2, hbuf);
    matmul_kernel<__bf16, true><<<512, 256, 0, stream>>>(hbuf, W3, dinv, tbuf);
    gather_pool_kernel<<<nblk_pool, 256, 0, stream>>>(t32, row_ptr, esrc, dinv,
                                                      b3, batch, (float*)d_out);
}